// Round 17
// baseline (200.916 us; speedup 1.0000x reference)
//
#include <hip/hip_runtime.h>
#include <hip/hip_bf16.h>
#include <stdint.h>

// B=2, T=2048, D=2048, NH=16, NKV=4, HD=128.  qkv width = 3072 (q 0..2047, k 2048..2559, v 2560..3071)

typedef __attribute__((ext_vector_type(8))) short short8;
typedef __attribute__((ext_vector_type(4))) float f32x4;
typedef __attribute__((ext_vector_type(16))) float f32x16;

#define GLOAD16(gp, lp) \
  __builtin_amdgcn_global_load_lds((const __attribute__((address_space(1))) void*)(gp), \
                                   (__attribute__((address_space(3))) void*)(lp), 16, 0, 0)

#define BAR() do { asm volatile("" ::: "memory"); __builtin_amdgcn_s_barrier(); asm volatile("" ::: "memory"); } while (0)

__device__ __forceinline__ float bf2f(unsigned short u) {
  union { unsigned int i; float f; } v; v.i = ((unsigned int)u) << 16; return v.f;
}
__device__ __forceinline__ unsigned short f2bf(float f) {
  union { float fl; unsigned int i; } v; v.fl = f;
  unsigned int r = v.i + 0x7fffu + ((v.i >> 16) & 1u);
  return (unsigned short)(r >> 16);
}
__device__ __forceinline__ unsigned pk2(float a, float b) {
  return (unsigned)f2bf(a) | ((unsigned)f2bf(b) << 16);
}

// ---------------- prep: f32->bf16 conversions + rope tables ----------------
__global__ __launch_bounds__(256) void prep_kernel(
    const float* __restrict__ x, const float* __restrict__ qw,
    const float* __restrict__ kw, const float* __restrict__ vw,
    const float* __restrict__ ow,
    unsigned short* __restrict__ xb, unsigned short* __restrict__ wqkv,
    unsigned short* __restrict__ owb, float* __restrict__ cost, float* __restrict__ sint) {
  const int NX = 2097152;   // x elems/4
  const int NW = 1572864;   // wqkv elems/4
  const int NO = 1048576;   // ow elems/4
  const int NT = 131072;    // table entries (2048*64)
  int tid = blockIdx.x * 256 + threadIdx.x;
  if (tid < NX) {
    float4 v = ((const float4*)x)[tid];
    uint2 o; o.x = pk2(v.x, v.y); o.y = pk2(v.z, v.w);
    ((uint2*)xb)[tid] = o;
  } else if (tid < NX + NW) {
    int i = tid - NX; int e = i * 4;
    const float* src = (e < 4194304) ? (qw + e)
                     : (e < 5242880) ? (kw + (e - 4194304))
                                     : (vw + (e - 5242880));
    float4 v = *(const float4*)src;
    uint2 o; o.x = pk2(v.x, v.y); o.y = pk2(v.z, v.w);
    ((uint2*)wqkv)[i] = o;
  } else if (tid < NX + NW + NO) {
    int i = tid - NX - NW;
    float4 v = ((const float4*)ow)[i];
    uint2 o; o.x = pk2(v.x, v.y); o.y = pk2(v.z, v.w);
    ((uint2*)owb)[i] = o;
  } else if (tid < NX + NW + NO + NT) {
    int i = tid - NX - NW - NO;
    int t = i >> 6, j = i & 63;
    // T(2048) > TSL(1024) branch: inv = 1/(10000 * 2^((128/126)^(j/64)))
    float e = exp2f(0.02272008f * (float)j * (1.0f / 64.0f));   // (128/126)^(j/64)
    float inv = 1.0f / (10000.0f * exp2f(e));
    float f = (float)t * inv;
    cost[i] = cosf(f);
    sint[i] = sinf(f);
  }
}

// ---------------- GEMM 4x2-phase: C = A @ Bw^T  (bf16 in, bf16/f32 out) -----
// (unchanged from R9 — verified)
template <int IM, int NB, int OUTF>
__global__ __launch_bounds__(512) void gemm8ph(const unsigned short* __restrict__ A,
                                               const unsigned short* __restrict__ Bw,
                                               void* __restrict__ Cp,
                                               int MT, int NTn, int N, int K) {
  extern __shared__ char smc[];
  constexpr int S = IM * 8;
  constexpr int IQ = IM / 2;
  constexpr int JQ = NB / 128;
  constexpr int ASZ = IM * 2048;
  constexpr int BSZ = NB * 64;
  constexpr int DB = 2 * ASZ + 2 * BSZ;
  constexpr int AL = (IM * 128) / 512;
  constexpr int BL = NB / 128;
  constexpr int VMCN = AL + 2 * BL;
  const int tid = threadIdx.x;
  const int l = tid & 63, w = tid >> 6;
  const int lane_r = l & 15, lane_g = l >> 4;
  const int wr = w >> 2, wc = w & 3;

  int qch = (MT * NTn) >> 3;
  int orig = blockIdx.x;
  int wgid = (orig & 7) * qch + (orig >> 3);
  int by = wgid / NTn, bx = wgid - by * NTn;
  const int m0 = by * IM * 32, n0 = bx * NB;

  f32x4 acc[IM][2 * JQ];
#pragma unroll
  for (int i = 0; i < IM; ++i)
#pragma unroll
    for (int j = 0; j < 2 * JQ; ++j) acc[i][j] = {0.f, 0.f, 0.f, 0.f};

  const unsigned short* srcA[AL]; int ldA[AL];
#pragma unroll
  for (int t = 0; t < AL; ++t) {
    int idx = t * 512 + tid;
    int rc = idx >> 3, kc = idx & 7;
    int wrp = rc >= S ? 1 : 0, rr = rc & (S - 1);
    int row = wrp * 2 * S + rr;
    srcA[t] = A + (size_t)(m0 + row) * K + (kc ^ (rc & 7)) * 8;
    ldA[t] = idx * 16;
  }
  const unsigned short* srcB[BL]; int ldB[BL];
#pragma unroll
  for (int t = 0; t < BL; ++t) {
    int idx = t * 512 + tid;
    int rc = idx >> 3, kc = idx & 7;
    int g16 = rc >> 4;
    int nrow = (g16 / JQ) * (NB / 4) + (g16 % JQ) * 16 + (rc & 15);
    srcB[t] = Bw + (size_t)(n0 + nrow) * K + (kc ^ (rc & 7)) * 8;
    ldB[t] = idx * 16;
  }
  const int SK = S * K, JK = (NB / 8) * K;

  auto STA = [&](int kt, int ih, int dqb) {
    char* d = smc + dqb + ih * ASZ;
#pragma unroll
    for (int t = 0; t < AL; ++t) GLOAD16(srcA[t] + kt + ih * SK, d + ldA[t]);
  };
  auto STB = [&](int kt, int jh, int dqb) {
    char* d = smc + dqb + 2 * ASZ + jh * BSZ;
#pragma unroll
    for (int t = 0; t < BL; ++t) GLOAD16(srcB[t] + kt + jh * JK, d + ldB[t]);
  };

  int oA[IQ][2], oB[JQ][2];
#pragma unroll
  for (int iq = 0; iq < IQ; ++iq)
#pragma unroll
    for (int ks = 0; ks < 2; ++ks) {
      int rc = wr * S + iq * 16 + lane_r;
      oA[iq][ks] = rc * 128 + ((ks * 64 + lane_g * 16) ^ ((rc & 7) << 4));
    }
#pragma unroll
  for (int jj = 0; jj < JQ; ++jj)
#pragma unroll
    for (int ks = 0; ks < 2; ++ks) {
      int rc = wc * (NB / 8) + jj * 16 + lane_r;
      oB[jj][ks] = rc * 128 + ((ks * 64 + lane_g * 16) ^ ((rc & 7) << 4));
    }

#define VMC() asm volatile("s_waitcnt vmcnt(%0)" :: "i"(VMCN) : "memory")
#define VM0() asm volatile("s_waitcnt vmcnt(0)" ::: "memory")
#define MM(IH, JH, BR) do { \
    __builtin_amdgcn_s_setprio(1); \
    _Pragma("unroll") \
    for (int iq = 0; iq < IQ; ++iq) \
      _Pragma("unroll") \
      for (int jj = 0; jj < JQ; ++jj) \
        _Pragma("unroll") \
        for (int ks = 0; ks < 2; ++ks) \
          acc[(IH) * IQ + iq][(JH) * JQ + jj] = __builtin_amdgcn_mfma_f32_16x16x32_bf16( \
              af[iq][ks], BR[jj][ks], acc[(IH) * IQ + iq][(JH) * JQ + jj], 0, 0, 0); \
    __builtin_amdgcn_s_setprio(0); } while (0)

  const int NS = K >> 6;
  STA(0, 0, 0); STB(0, 0, 0); STB(0, 1, 0); STA(0, 1, 0);
  STA(64, 0, DB); STB(64, 0, DB); STB(64, 1, DB);
  VMC();
  BAR();

#pragma unroll 1
  for (int s = 0; s < NS; ++s) {
    const int dq = (s & 1) * DB, dn = DB - dq;
    const char* Ab = smc + dq;
    const char* Bb = Ab + 2 * ASZ;
    short8 af[IQ][2], b0[JQ][2], b1[JQ][2];
    if (s + 1 < NS) STA((s + 1) << 6, 1, dn);
#pragma unroll
    for (int iq = 0; iq < IQ; ++iq)
#pragma unroll
      for (int ks = 0; ks < 2; ++ks) af[iq][ks] = *(const short8*)(Ab + oA[iq][ks]);
#pragma unroll
    for (int jj = 0; jj < JQ; ++jj)
#pragma unroll
      for (int ks = 0; ks < 2; ++ks) b0[jj][ks] = *(const short8*)(Bb + oB[jj][ks]);
    MM(0, 0, b0);
    BAR();
    if (s + 2 < NS) STA((s + 2) << 6, 0, dq);
#pragma unroll
    for (int jj = 0; jj < JQ; ++jj)
#pragma unroll
      for (int ks = 0; ks < 2; ++ks) b1[jj][ks] = *(const short8*)(Bb + BSZ + oB[jj][ks]);
    MM(0, 1, b1);
    BAR();
    if (s + 2 < NS) STB((s + 2) << 6, 0, dq);
#pragma unroll
    for (int iq = 0; iq < IQ; ++iq)
#pragma unroll
      for (int ks = 0; ks < 2; ++ks) af[iq][ks] = *(const short8*)(Ab + ASZ + oA[iq][ks]);
    MM(1, 0, b0);
    BAR();
    if (s + 2 < NS) STB((s + 2) << 6, 1, dq);
    MM(1, 1, b1);
    if (s + 2 < NS) VMC(); else VM0();
    BAR();
  }
#undef VMC
#undef VM0
#undef MM

#pragma unroll
  for (int ih = 0; ih < 2; ++ih)
#pragma unroll
    for (int iq = 0; iq < IQ; ++iq) {
      int row = m0 + wr * 2 * S + ih * S + iq * 16 + lane_g * 4;
#pragma unroll
      for (int jh = 0; jh < 2; ++jh)
#pragma unroll
        for (int jj = 0; jj < JQ; ++jj) {
          int col = n0 + wc * (NB / 4) + jh * (NB / 8) + jj * 16 + lane_r;
#pragma unroll
          for (int r = 0; r < 4; ++r) {
            float v = acc[ih * IQ + iq][jh * JQ + jj][r];
            if (OUTF)
              ((float*)Cp)[(size_t)(row + r) * N + col] = v;
            else
              ((unsigned short*)Cp)[(size_t)(row + r) * N + col] = f2bf(v);
          }
        }
    }
}

// ------- fused RMSNorm+RoPE (+qg, scale, log2e) AND V-transpose (merged) ----
__global__ __launch_bounds__(256) void normrope_vt_kernel(unsigned short* __restrict__ qkv,
                                                          const float* __restrict__ cost,
                                                          const float* __restrict__ sint,
                                                          const float* __restrict__ qg,
                                                          unsigned short* __restrict__ vtg) {
  __shared__ unsigned short tile[64][132];   // used by vtrans blocks only
  int bid = blockIdx.x;
  const int tid = threadIdx.x;
  if (bid < 20480) {
    const int l = tid & 63, w = tid >> 6;
    int row = bid * 4 + w;                 // 0 .. 81919
    int tok = row / 20, hh = row - tok * 20;
    int t = tok & 2047;
    bool isq = hh < 16;
    int col0 = isq ? hh * 128 : 2048 + (hh - 16) * 128;
    unsigned short* p = qkv + (size_t)tok * 3072 + col0 + 2 * l;
    unsigned int u = *(const unsigned int*)p;
    float x0 = bf2f((unsigned short)(u & 0xffffu));
    float x1 = bf2f((unsigned short)(u >> 16));
    float ss = x0 * x0 + x1 * x1;
#pragma unroll
    for (int m = 1; m < 64; m <<= 1) ss += __shfl_xor(ss, m);
    float rn = rsqrtf(ss * (1.0f / 128.0f) + 1.1920928955078125e-07f);
    float n0 = x0 * rn, n1 = x1 * rn;
    float p0 = __shfl_xor(n0, 32);
    float p1 = __shfl_xor(n1, 32);
    int jj = (2 * l) & 63;
    float c0 = cost[t * 64 + jj], c1 = cost[t * 64 + jj + 1];
    float s0 = sint[t * 64 + jj], s1 = sint[t * 64 + jj + 1];
    float o0, o1;
    if (l < 32) { o0 = n0 * c0 + p0 * s0; o1 = n1 * c1 + p1 * s1; }
    else        { o0 = -p0 * s0 + n0 * c0; o1 = -p1 * s1 + n1 * c1; }
    // fold 1/sqrt(128) AND log2(e) into q so attention scores are in log2 units
    if (isq) { float g = qg[hh] * 0.08838834764831845f * 1.4426950408889634f; o0 *= g; o1 *= g; }
    *(unsigned int*)p = pk2(o0, o1);
  } else {
    int bid2 = bid - 20480;                  // 0..255
    int pan = bid2 & 7, tt = bid2 >> 3;
    int b = pan >> 2, kvh = pan & 3;
    int t0 = tt * 64;
    const unsigned short* src = qkv + ((size_t)(b * 2048 + t0)) * 3072 + 2560 + kvh * 128;
#pragma unroll
    for (int i = 0; i < 8; ++i) {
      int idx = i * 256 + tid;
      int row = idx >> 5, c4 = idx & 31;
      uint2 v = *(const uint2*)(src + (size_t)row * 3072 + c4 * 4);
      *(uint2*)&tile[row][c4 * 4] = v;
    }
    __syncthreads();
    unsigned short* dst = vtg + (size_t)pan * 262144 + t0;
#pragma unroll
    for (int i = 0; i < 8; ++i) {
      int idx = i * 256 + tid;
      int d = idx >> 4, tc = idx & 15;
      unsigned short a0 = tile[tc * 4 + 0][d], a1 = tile[tc * 4 + 1][d];
      unsigned short a2 = tile[tc * 4 + 2][d], a3 = tile[tc * 4 + 3][d];
      uint2 o; o.x = (unsigned)a0 | ((unsigned)a1 << 16);
      o.y = (unsigned)a2 | ((unsigned)a3 << 16);
      *(uint2*)(dst + (size_t)d * 2048 + tc * 4) = o;
    }
  }
}

// ---------------- flash attention v13: fa7 dataflow, 512 blocks, 2 blocks/CU -
// fa7 (R9-verified, 104 VGPR, 67584 B LDS) with the sequential pair SPLIT
// across blocks: n<256 = long tile (qt=15-pi), n>=256 = short tile (qt=pi).
// In-order dispatch pairs one long + one short per CU -> 16 waves/CU during
// overlap, 8 after the short drains (= fa10 baseline). 8 waves = 4 q-grp x
// 2 k-half, split-k + merge, KVBLK=64, K/V^T dbuf. T12 in-reg P, T13 defer-max.
__global__ __launch_bounds__(512) void attn_fa13(const unsigned short* __restrict__ qkv,
                                                 const unsigned short* __restrict__ vtg,
                                                 unsigned short* __restrict__ y) {
  extern __shared__ char smc[];
  const int tid = threadIdx.x;
  const int l = tid & 63, w = tid >> 6;      // 8 waves
  const int lq = l & 31, hi = l >> 5;
  const int g = w & 3, hh = w >> 2;          // q-group, k-half

  int n = blockIdx.x;
  int n8 = n & 255;
  int pan = n8 & 7;           // panel -> XCD
  int b = pan >> 2, kvh = pan & 3;
  int idx2 = n8 >> 3;
  int h = kvh * 4 + (idx2 & 3);
  int pairIdx = idx2 >> 2;    // 0..7
  const int qt = (n >= 256) ? pairIdx : 15 - pairIdx;   // long tiles dispatch first
  const size_t rowbase = (size_t)b * 2048;
  const unsigned short* kvK = qkv + rowbase * 3072;
  const unsigned short* vtp = vtg + (size_t)pan * 262144;

  // staging descriptors (2 chunks each for K and V^T; 512 threads)
  int kg[2], vg[2], sl[2];
#pragma unroll
  for (int t = 0; t < 2; ++t) {
    int idx = t * 512 + tid;
    { int row = idx >> 4, c = idx & 15, gc = c ^ (row & 7);
      kg[t] = row * 3072 + 2048 + kvh * 128 + gc * 8; }
    { int d = idx >> 3, c = idx & 7, gc = c ^ (d & 7);
      vg[t] = d * 2048 + gc * 8; }
    sl[t] = idx * 16;
  }
  const int swq = (lq & 7) << 4;
  const int krow = (hh * 32 + lq) * 256;   // K row byte (this wave's k-half)
  int oxk[8];
#pragma unroll
  for (int ds = 0; ds < 8; ++ds) oxk[ds] = (ds * 32 + hi * 16) ^ swq;
  const int vrow = lq * 128;               // V^T row byte (d row, dt adds 4096)
  int oxv[2];
#pragma unroll
  for (int ksl = 0; ksl < 2; ++ksl) oxv[ksl] = (hh * 64 + ksl * 32 + hi * 16) ^ swq;
  // merge regions (K/V dbuf area dead at merge time)
  const int mab = (g * 64 + l) * 256;        // acc spill in [0, 64K)
  const int mlb = 65536 + (g * 64 + l) * 8;  // m,l spill (2KB tail)
  const int lsw = (l & 7) << 4;

  auto STAGE = [&](int tile, int bufsel) {
    const unsigned short* srcK = kvK + (size_t)tile * 64 * 3072;
    const unsigned short* srcV = vtp + tile * 64;
    char* kd = smc + bufsel * 16384;
    char* vd = smc + 32768 + bufsel * 16384;
#pragma unroll
    for (int t = 0; t < 2; ++t) {
      GLOAD16(srcK + kg[t], kd + sl[t]);
      GLOAD16(srcV + vg[t], vd + sl[t]);
    }
  };

  const int q0 = qt * 128;
  const int nkb = 2 * qt + 2;
  const int wrow0 = q0 + g * 32;
  const int qrow = wrow0 + lq;

  STAGE(0, 0);
  short8 qf[8];
#pragma unroll
  for (int ds = 0; ds < 8; ++ds)
    qf[ds] = *(const short8*)(qkv + (rowbase + qrow) * 3072 + h * 128 + ds * 16 + hi * 8);

  f32x16 acc[4];
#pragma unroll
  for (int dt = 0; dt < 4; ++dt)
#pragma unroll
    for (int jj = 0; jj < 16; ++jj) acc[dt][jj] = 0.f;
  float mrun = -1e30f, lrun = 0.f;

  __syncthreads();   // tile 0 resident

#pragma unroll 1
  for (int kb = 0; kb < nkb; ++kb) {
    const int cur = kb & 1;
    if (kb + 1 < nkb) STAGE(kb + 1, cur ^ 1);   // prefetch overlaps compute
    const int j0 = kb * 64;
    if (j0 + hh * 32 <= wrow0) {                // wave-active (k-half causal)
      const int kbb = cur * 16384;
      const int vbb = 32768 + cur * 16384;
      // ---- S^T = K @ Q^T : one 32x32 tile; k = (jj&3)+8*(jj>>2)+4hi, q = lq
      f32x16 s;
#pragma unroll
      for (int jj = 0; jj < 16; ++jj) s[jj] = 0.f;
      __builtin_amdgcn_s_setprio(1);
#pragma unroll
      for (int ds = 0; ds < 8; ++ds) {
        short8 kf = *(const short8*)(smc + kbb + krow + oxk[ds]);
        s = __builtin_amdgcn_mfma_f32_32x32x16_bf16(kf, qf[ds], s, 0, 0, 0);
      }
      __builtin_amdgcn_s_setprio(0);
      // ---- causal mask (local) ----
      const int rq = qrow - j0 - hh * 32;
      if (rq < 31) {
#pragma unroll
        for (int jj = 0; jj < 16; ++jj) {
          int kl = (jj & 3) + 8 * (jj >> 2) + 4 * hi;
          s[jj] = (kl > rq) ? -1e30f : s[jj];
        }
      }
      // ---- online softmax (exp2 units), T13 defer-max ----
      float pmax = s[0];
#pragma unroll
      for (int jj = 1; jj < 16; ++jj) pmax = fmaxf(pmax, s[jj]);
      pmax = fmaxf(pmax, __shfl_xor(pmax, 32));
      if (!__all(pmax - mrun <= 11.5f)) {
        float mn = fmaxf(mrun, pmax);
        float corr = exp2f(mrun - mn);
        lrun *= corr;
#pragma unroll
        for (int dt = 0; dt < 4; ++dt)
#pragma unroll
          for (int jj = 0; jj < 16; ++jj) acc[dt][jj] *= corr;
        mrun = mn;
      }
      float rs = 0.f;
#pragma unroll
      for (int jj = 0; jj < 16; ++jj) { s[jj] = exp2f(s[jj] - mrun); rs += s[jj]; }
      rs += __shfl_xor(rs, 32);
      lrun += rs;
      // ---- P -> bf16 in registers (T12) ----
      unsigned r[8];
#pragma unroll
      for (int j = 0; j < 4; ++j) {
        asm("v_cvt_pk_bf16_f32 %0, %1, %2" : "=v"(r[2 * j]) : "v"(s[4 * j]), "v"(s[4 * j + 1]));
        asm("v_cvt_pk_bf16_f32 %0, %1, %2" : "=v"(r[2 * j + 1]) : "v"(s[4 * j + 2]), "v"(s[4 * j + 3]));
      }
      // ---- O^T += V^T @ P^T : B-frags via permlane32_swap (T12) ----
      __builtin_amdgcn_s_setprio(1);
#pragma unroll
      for (int ksl = 0; ksl < 2; ++ksl) {
        unsigned w0 = r[4 * ksl], w2 = r[4 * ksl + 2];
        asm("v_permlane32_swap_b32 %0, %1" : "+v"(w0), "+v"(w2));
        unsigned w1 = r[4 * ksl + 1], w3 = r[4 * ksl + 3];
        asm("v_permlane32_swap_b32 %0, %1" : "+v"(w1), "+v"(w3));
        union { unsigned u[4]; short8 s8; } pu;
        pu.u[0] = w0; pu.u[1] = w1; pu.u[2] = w2; pu.u[3] = w3;
        short8 pf = pu.s8;
#pragma unroll
        for (int dt = 0; dt < 4; ++dt) {
          short8 vf = *(const short8*)(smc + vbb + dt * 4096 + vrow + oxv[ksl]);
          acc[dt] = __builtin_amdgcn_mfma_f32_32x32x16_bf16(vf, pf, acc[dt], 0, 0, 0);
        }
      }
      __builtin_amdgcn_s_setprio(0);
    }
    __syncthreads();   // prefetch drained; all waves done with cur bufs
  }
  // ---- split-k merge: upper half-waves spill, lower combine ----
  if (hh) {
#pragma unroll
    for (int dt = 0; dt < 4; ++dt)
#pragma unroll
      for (int q4 = 0; q4 < 4; ++q4) {
        f32x4 v = {acc[dt][4 * q4], acc[dt][4 * q4 + 1], acc[dt][4 * q4 + 2], acc[dt][4 * q4 + 3]};
        *(f32x4*)(smc + mab + ((dt * 64 + q4 * 16) ^ lsw)) = v;
      }
    *(float2*)(smc + mlb) = {mrun, lrun};
  }
  __syncthreads();
  if (!hh) {
    float2 ml = *(const float2*)(smc + mlb);
    float mx = fmaxf(mrun, ml.x);
    float sc0 = exp2f(mrun - mx), sc1 = exp2f(ml.x - mx);
    lrun = lrun * sc0 + ml.y * sc1;
#pragma unroll
    for (int dt = 0; dt < 4; ++dt)
#pragma unroll
      for (int q4 = 0; q4 < 4; ++q4) {
        f32x4 v = *(const f32x4*)(smc + mab + ((dt * 64 + q4 * 16) ^ lsw));
#pragma unroll
        for (int r2 = 0; r2 < 4; ++r2)
          acc[dt][4 * q4 + r2] = acc[dt][4 * q4 + r2] * sc0 + v[r2] * sc1;
      }
    // ---- epilogue: O^T[d = dt*32 + r + 8m + 4hi][q=lq] ----
    float linv = 1.0f / lrun;
    unsigned short* yrow = y + (rowbase + qrow) * 2048 + h * 128;
#pragma unroll
    for (int dt = 0; dt < 4; ++dt)
#pragma unroll
      for (int m = 0; m < 4; ++m) {
        uint2 o;
        o.x = pk2(acc[dt][4 * m] * linv, acc[dt][4 * m + 1] * linv);
        o.y = pk2(acc[dt][4 * m + 2] * linv, acc[dt][4 * m + 3] * linv);
        *(uint2*)(yrow + dt * 32 + m * 8 + hi * 4) = o;
      }
  }
}

// ---------------- launch ----------------
extern "C" void kernel_launch(void* const* d_in, const int* in_sizes, int n_in,
                              void* d_out, int out_size, void* d_ws, size_t ws_size,
                              hipStream_t stream) {
  (void)in_sizes; (void)n_in; (void)out_size; (void)ws_size;
  const float* x  = (const float*)d_in[0];
  const float* qw = (const float*)d_in[1];
  const float* kw = (const float*)d_in[2];
  const float* vw = (const float*)d_in[3];
  const float* ow = (const float*)d_in[4];
  const float* qg = (const float*)d_in[5];

  char* ws = (char*)d_ws;
  unsigned short* xb   = (unsigned short*)(ws + 0);          // dead after gemm1
  unsigned short* vtg  = (unsigned short*)(ws + 0);          // aliases xb (4 MB)
  unsigned short* wqkv = (unsigned short*)(ws + 16777216);
  unsigned short* owb  = (unsigned short*)(ws + 29360128);
  unsigned short* qkvb = (unsigned short*)(ws + 37748736);
  unsigned short* y    = (unsigned short*)(ws + 62914560);
  float* cost          = (float*)(ws + 79691776);
  float* sint          = (float*)(ws + 80216064);

  prep_kernel<<<18944, 256, 0, stream>>>(x, qw, kw, vw, ow, xb, wqkv, owb, cost, sint);
  gemm8ph<4, 384, 0><<<256, 512, 131072, stream>>>(xb, wqkv, qkvb, 32, 8, 3072, 2048);
  normrope_vt_kernel<<<20736, 256, 0, stream>>>(qkvb, cost, sint, qg, vtg);
  attn_fa13<<<512, 512, 67584, stream>>>(qkvb, vtg, y);
  gemm8ph<4, 256, 1><<<256, 512, 98304, stream>>>(y, owb, d_out, 32, 8, 2048, 2048);
}

// Round 18
// 186.159 us; speedup vs baseline: 1.0793x; 1.0793x over previous
//
#include <hip/hip_runtime.h>
#include <hip/hip_bf16.h>
#include <stdint.h>

// B=2, T=2048, D=2048, NH=16, NKV=4, HD=128.  qkv width = 3072 (q 0..2047, k 2048..2559, v 2560..3071)

typedef __attribute__((ext_vector_type(8))) short short8;
typedef __attribute__((ext_vector_type(4))) float f32x4;
typedef __attribute__((ext_vector_type(16))) float f32x16;

#define GLOAD16(gp, lp) \
  __builtin_amdgcn_global_load_lds((const __attribute__((address_space(1))) void*)(gp), \
                                   (__attribute__((address_space(3))) void*)(lp), 16, 0, 0)

#define BAR() do { asm volatile("" ::: "memory"); __builtin_amdgcn_s_barrier(); asm volatile("" ::: "memory"); } while (0)

__device__ __forceinline__ float bf2f(unsigned short u) {
  union { unsigned int i; float f; } v; v.i = ((unsigned int)u) << 16; return v.f;
}
__device__ __forceinline__ unsigned short f2bf(float f) {
  union { float fl; unsigned int i; } v; v.fl = f;
  unsigned int r = v.i + 0x7fffu + ((v.i >> 16) & 1u);
  return (unsigned short)(r >> 16);
}
__device__ __forceinline__ unsigned pk2(float a, float b) {
  return (unsigned)f2bf(a) | ((unsigned)f2bf(b) << 16);
}

// ---------------- prep: f32->bf16 conversions + rope tables ----------------
__global__ __launch_bounds__(256) void prep_kernel(
    const float* __restrict__ x, const float* __restrict__ qw,
    const float* __restrict__ kw, const float* __restrict__ vw,
    const float* __restrict__ ow,
    unsigned short* __restrict__ xb, unsigned short* __restrict__ wqkv,
    unsigned short* __restrict__ owb, float* __restrict__ cost, float* __restrict__ sint) {
  const int NX = 2097152;   // x elems/4
  const int NW = 1572864;   // wqkv elems/4
  const int NO = 1048576;   // ow elems/4
  const int NT = 131072;    // table entries (2048*64)
  int tid = blockIdx.x * 256 + threadIdx.x;
  if (tid < NX) {
    float4 v = ((const float4*)x)[tid];
    uint2 o; o.x = pk2(v.x, v.y); o.y = pk2(v.z, v.w);
    ((uint2*)xb)[tid] = o;
  } else if (tid < NX + NW) {
    int i = tid - NX; int e = i * 4;
    const float* src = (e < 4194304) ? (qw + e)
                     : (e < 5242880) ? (kw + (e - 4194304))
                                     : (vw + (e - 5242880));
    float4 v = *(const float4*)src;
    uint2 o; o.x = pk2(v.x, v.y); o.y = pk2(v.z, v.w);
    ((uint2*)wqkv)[i] = o;
  } else if (tid < NX + NW + NO) {
    int i = tid - NX - NW;
    float4 v = ((const float4*)ow)[i];
    uint2 o; o.x = pk2(v.x, v.y); o.y = pk2(v.z, v.w);
    ((uint2*)owb)[i] = o;
  } else if (tid < NX + NW + NO + NT) {
    int i = tid - NX - NW - NO;
    int t = i >> 6, j = i & 63;
    // T(2048) > TSL(1024) branch: inv = 1/(10000 * 2^((128/126)^(j/64)))
    float e = exp2f(0.02272008f * (float)j * (1.0f / 64.0f));   // (128/126)^(j/64)
    float inv = 1.0f / (10000.0f * exp2f(e));
    float f = (float)t * inv;
    cost[i] = cosf(f);
    sint[i] = sinf(f);
  }
}

// ---------------- GEMM 4x2-phase: C = A @ Bw^T  (bf16 in, bf16/f32 out) -----
// (unchanged from R9 — verified)
template <int IM, int NB, int OUTF>
__global__ __launch_bounds__(512) void gemm8ph(const unsigned short* __restrict__ A,
                                               const unsigned short* __restrict__ Bw,
                                               void* __restrict__ Cp,
                                               int MT, int NTn, int N, int K) {
  extern __shared__ char smc[];
  constexpr int S = IM * 8;
  constexpr int IQ = IM / 2;
  constexpr int JQ = NB / 128;
  constexpr int ASZ = IM * 2048;
  constexpr int BSZ = NB * 64;
  constexpr int DB = 2 * ASZ + 2 * BSZ;
  constexpr int AL = (IM * 128) / 512;
  constexpr int BL = NB / 128;
  constexpr int VMCN = AL + 2 * BL;
  const int tid = threadIdx.x;
  const int l = tid & 63, w = tid >> 6;
  const int lane_r = l & 15, lane_g = l >> 4;
  const int wr = w >> 2, wc = w & 3;

  int qch = (MT * NTn) >> 3;
  int orig = blockIdx.x;
  int wgid = (orig & 7) * qch + (orig >> 3);
  int by = wgid / NTn, bx = wgid - by * NTn;
  const int m0 = by * IM * 32, n0 = bx * NB;

  f32x4 acc[IM][2 * JQ];
#pragma unroll
  for (int i = 0; i < IM; ++i)
#pragma unroll
    for (int j = 0; j < 2 * JQ; ++j) acc[i][j] = {0.f, 0.f, 0.f, 0.f};

  const unsigned short* srcA[AL]; int ldA[AL];
#pragma unroll
  for (int t = 0; t < AL; ++t) {
    int idx = t * 512 + tid;
    int rc = idx >> 3, kc = idx & 7;
    int wrp = rc >= S ? 1 : 0, rr = rc & (S - 1);
    int row = wrp * 2 * S + rr;
    srcA[t] = A + (size_t)(m0 + row) * K + (kc ^ (rc & 7)) * 8;
    ldA[t] = idx * 16;
  }
  const unsigned short* srcB[BL]; int ldB[BL];
#pragma unroll
  for (int t = 0; t < BL; ++t) {
    int idx = t * 512 + tid;
    int rc = idx >> 3, kc = idx & 7;
    int g16 = rc >> 4;
    int nrow = (g16 / JQ) * (NB / 4) + (g16 % JQ) * 16 + (rc & 15);
    srcB[t] = Bw + (size_t)(n0 + nrow) * K + (kc ^ (rc & 7)) * 8;
    ldB[t] = idx * 16;
  }
  const int SK = S * K, JK = (NB / 8) * K;

  auto STA = [&](int kt, int ih, int dqb) {
    char* d = smc + dqb + ih * ASZ;
#pragma unroll
    for (int t = 0; t < AL; ++t) GLOAD16(srcA[t] + kt + ih * SK, d + ldA[t]);
  };
  auto STB = [&](int kt, int jh, int dqb) {
    char* d = smc + dqb + 2 * ASZ + jh * BSZ;
#pragma unroll
    for (int t = 0; t < BL; ++t) GLOAD16(srcB[t] + kt + jh * JK, d + ldB[t]);
  };

  int oA[IQ][2], oB[JQ][2];
#pragma unroll
  for (int iq = 0; iq < IQ; ++iq)
#pragma unroll
    for (int ks = 0; ks < 2; ++ks) {
      int rc = wr * S + iq * 16 + lane_r;
      oA[iq][ks] = rc * 128 + ((ks * 64 + lane_g * 16) ^ ((rc & 7) << 4));
    }
#pragma unroll
  for (int jj = 0; jj < JQ; ++jj)
#pragma unroll
    for (int ks = 0; ks < 2; ++ks) {
      int rc = wc * (NB / 8) + jj * 16 + lane_r;
      oB[jj][ks] = rc * 128 + ((ks * 64 + lane_g * 16) ^ ((rc & 7) << 4));
    }

#define VMC() asm volatile("s_waitcnt vmcnt(%0)" :: "i"(VMCN) : "memory")
#define VM0() asm volatile("s_waitcnt vmcnt(0)" ::: "memory")
#define MM(IH, JH, BR) do { \
    __builtin_amdgcn_s_setprio(1); \
    _Pragma("unroll") \
    for (int iq = 0; iq < IQ; ++iq) \
      _Pragma("unroll") \
      for (int jj = 0; jj < JQ; ++jj) \
        _Pragma("unroll") \
        for (int ks = 0; ks < 2; ++ks) \
          acc[(IH) * IQ + iq][(JH) * JQ + jj] = __builtin_amdgcn_mfma_f32_16x16x32_bf16( \
              af[iq][ks], BR[jj][ks], acc[(IH) * IQ + iq][(JH) * JQ + jj], 0, 0, 0); \
    __builtin_amdgcn_s_setprio(0); } while (0)

  const int NS = K >> 6;
  STA(0, 0, 0); STB(0, 0, 0); STB(0, 1, 0); STA(0, 1, 0);
  STA(64, 0, DB); STB(64, 0, DB); STB(64, 1, DB);
  VMC();
  BAR();

#pragma unroll 1
  for (int s = 0; s < NS; ++s) {
    const int dq = (s & 1) * DB, dn = DB - dq;
    const char* Ab = smc + dq;
    const char* Bb = Ab + 2 * ASZ;
    short8 af[IQ][2], b0[JQ][2], b1[JQ][2];
    if (s + 1 < NS) STA((s + 1) << 6, 1, dn);
#pragma unroll
    for (int iq = 0; iq < IQ; ++iq)
#pragma unroll
      for (int ks = 0; ks < 2; ++ks) af[iq][ks] = *(const short8*)(Ab + oA[iq][ks]);
#pragma unroll
    for (int jj = 0; jj < JQ; ++jj)
#pragma unroll
      for (int ks = 0; ks < 2; ++ks) b0[jj][ks] = *(const short8*)(Bb + oB[jj][ks]);
    MM(0, 0, b0);
    BAR();
    if (s + 2 < NS) STA((s + 2) << 6, 0, dq);
#pragma unroll
    for (int jj = 0; jj < JQ; ++jj)
#pragma unroll
      for (int ks = 0; ks < 2; ++ks) b1[jj][ks] = *(const short8*)(Bb + BSZ + oB[jj][ks]);
    MM(0, 1, b1);
    BAR();
    if (s + 2 < NS) STB((s + 2) << 6, 0, dq);
#pragma unroll
    for (int iq = 0; iq < IQ; ++iq)
#pragma unroll
      for (int ks = 0; ks < 2; ++ks) af[iq][ks] = *(const short8*)(Ab + ASZ + oA[iq][ks]);
    MM(1, 0, b0);
    BAR();
    if (s + 2 < NS) STB((s + 2) << 6, 1, dq);
    MM(1, 1, b1);
    if (s + 2 < NS) VMC(); else VM0();
    BAR();
  }
#undef VMC
#undef VM0
#undef MM

#pragma unroll
  for (int ih = 0; ih < 2; ++ih)
#pragma unroll
    for (int iq = 0; iq < IQ; ++iq) {
      int row = m0 + wr * 2 * S + ih * S + iq * 16 + lane_g * 4;
#pragma unroll
      for (int jh = 0; jh < 2; ++jh)
#pragma unroll
        for (int jj = 0; jj < JQ; ++jj) {
          int col = n0 + wc * (NB / 4) + jh * (NB / 8) + jj * 16 + lane_r;
#pragma unroll
          for (int r = 0; r < 4; ++r) {
            float v = acc[ih * IQ + iq][jh * JQ + jj][r];
            if (OUTF)
              ((float*)Cp)[(size_t)(row + r) * N + col] = v;
            else
              ((unsigned short*)Cp)[(size_t)(row + r) * N + col] = f2bf(v);
          }
        }
    }
}

// ------- fused RMSNorm+RoPE (+qg, scale, log2e) AND V-transpose (merged) ----
__global__ __launch_bounds__(256) void normrope_vt_kernel(unsigned short* __restrict__ qkv,
                                                          const float* __restrict__ cost,
                                                          const float* __restrict__ sint,
                                                          const float* __restrict__ qg,
                                                          unsigned short* __restrict__ vtg) {
  __shared__ unsigned short tile[64][132];   // used by vtrans blocks only
  int bid = blockIdx.x;
  const int tid = threadIdx.x;
  if (bid < 20480) {
    const int l = tid & 63, w = tid >> 6;
    int row = bid * 4 + w;                 // 0 .. 81919
    int tok = row / 20, hh = row - tok * 20;
    int t = tok & 2047;
    bool isq = hh < 16;
    int col0 = isq ? hh * 128 : 2048 + (hh - 16) * 128;
    unsigned short* p = qkv + (size_t)tok * 3072 + col0 + 2 * l;
    unsigned int u = *(const unsigned int*)p;
    float x0 = bf2f((unsigned short)(u & 0xffffu));
    float x1 = bf2f((unsigned short)(u >> 16));
    float ss = x0 * x0 + x1 * x1;
#pragma unroll
    for (int m = 1; m < 64; m <<= 1) ss += __shfl_xor(ss, m);
    float rn = rsqrtf(ss * (1.0f / 128.0f) + 1.1920928955078125e-07f);
    float n0 = x0 * rn, n1 = x1 * rn;
    float p0 = __shfl_xor(n0, 32);
    float p1 = __shfl_xor(n1, 32);
    int jj = (2 * l) & 63;
    float c0 = cost[t * 64 + jj], c1 = cost[t * 64 + jj + 1];
    float s0 = sint[t * 64 + jj], s1 = sint[t * 64 + jj + 1];
    float o0, o1;
    if (l < 32) { o0 = n0 * c0 + p0 * s0; o1 = n1 * c1 + p1 * s1; }
    else        { o0 = -p0 * s0 + n0 * c0; o1 = -p1 * s1 + n1 * c1; }
    // fold 1/sqrt(128) AND log2(e) into q so attention scores are in log2 units
    if (isq) { float g = qg[hh] * 0.08838834764831845f * 1.4426950408889634f; o0 *= g; o1 *= g; }
    *(unsigned int*)p = pk2(o0, o1);
  } else {
    int bid2 = bid - 20480;                  // 0..255
    int pan = bid2 & 7, tt = bid2 >> 3;
    int b = pan >> 2, kvh = pan & 3;
    int t0 = tt * 64;
    const unsigned short* src = qkv + ((size_t)(b * 2048 + t0)) * 3072 + 2560 + kvh * 128;
#pragma unroll
    for (int i = 0; i < 8; ++i) {
      int idx = i * 256 + tid;
      int row = idx >> 5, c4 = idx & 31;
      uint2 v = *(const uint2*)(src + (size_t)row * 3072 + c4 * 4);
      *(uint2*)&tile[row][c4 * 4] = v;
    }
    __syncthreads();
    unsigned short* dst = vtg + (size_t)pan * 262144 + t0;
#pragma unroll
    for (int i = 0; i < 8; ++i) {
      int idx = i * 256 + tid;
      int d = idx >> 4, tc = idx & 15;
      unsigned short a0 = tile[tc * 4 + 0][d], a1 = tile[tc * 4 + 1][d];
      unsigned short a2 = tile[tc * 4 + 2][d], a3 = tile[tc * 4 + 3][d];
      uint2 o; o.x = (unsigned)a0 | ((unsigned)a1 << 16);
      o.y = (unsigned)a2 | ((unsigned)a3 << 16);
      *(uint2*)(dst + (size_t)d * 2048 + tc * 4) = o;
    }
  }
}

// ---------------- flash attention v10: KVBLK=128, 17 tile-iters -------------
// (R12/R16 verified best: 70 us, 128 VGPR, no spill)
// 256 blocks, 8 waves = 4 q-grp x 2 k-half, sequential balanced tile pairs,
// split-k + end-of-phase merge. K[128][128] + V^T[128][128] dbuf swizzled
// (131072 B). Wave (g,hh): k-half hh (64 rows) = 2 QK subtiles + 4 PV k-slices.
// In-register P (T12), defer-max (T13).
__global__ __launch_bounds__(512) void attn_fa10(const unsigned short* __restrict__ qkv,
                                                 const unsigned short* __restrict__ vtg,
                                                 unsigned short* __restrict__ y) {
  extern __shared__ char smc[];
  const int tid = threadIdx.x;
  const int l = tid & 63, w = tid >> 6;      // 8 waves
  const int lq = l & 31, hi = l >> 5;
  const int g = w & 3, hh = w >> 2;          // q-group, k-half

  int n = blockIdx.x;
  int pan = n & 7;            // panel -> XCD
  int b = pan >> 2, kvh = pan & 3;
  int idx2 = n >> 3;
  int h = kvh * 4 + (idx2 & 3);
  int pairIdx = idx2 >> 2;    // 0..7
  const size_t rowbase = (size_t)b * 2048;
  const unsigned short* kvK = qkv + rowbase * 3072;
  const unsigned short* vtp = vtg + (size_t)pan * 262144;

  // staging descriptors: K 2048 chunks (4/thread), V 2048 chunks (4/thread)
  int kg[4], vg[4], sl[4];
#pragma unroll
  for (int t = 0; t < 4; ++t) {
    int idx = t * 512 + tid;
    int row = idx >> 4, c = idx & 15, gc = c ^ (row & 7);
    kg[t] = row * 3072 + 2048 + kvh * 128 + gc * 8;   // K row (tile-local), 128 rows
    vg[t] = row * 2048 + gc * 8;                      // V^T row d, cols tile-local
    sl[t] = idx * 16;
  }
  const int swq = (lq & 7) << 4;
  const int krow = (hh * 64 + lq) * 256;   // K row byte base (subtile 1: +8192)
  int oxk[8];
#pragma unroll
  for (int ds = 0; ds < 8; ++ds) oxk[ds] = (ds * 32 + hi * 16) ^ swq;
  const int vrow = lq * 256;               // V^T row byte (d row; dt adds 32*256)
  int oxv[4];                              // per k-slice of this wave's k-half
#pragma unroll
  for (int ksl = 0; ksl < 4; ++ksl) oxv[ksl] = (hh * 128 + ksl * 32 + hi * 16) ^ swq;
  // merge regions (aliases dead K/V buffers after the loop)
  const int mab = (g * 64 + l) * 256;        // acc spill in [0, 64K)
  const int mlb = 65536 + (g * 64 + l) * 8;  // m,l spill (V0 region, dead)
  const int lsw = (l & 7) << 4;

  auto STAGE = [&](int tile, int bufsel) {
    const unsigned short* srcK = kvK + (size_t)tile * 128 * 3072;
    const unsigned short* srcV = vtp + tile * 128;
    char* kd = smc + bufsel * 32768;
    char* vd = smc + 65536 + bufsel * 32768;
#pragma unroll
    for (int t = 0; t < 4; ++t) {
      GLOAD16(srcK + kg[t], kd + sl[t]);
      GLOAD16(srcV + vg[t], vd + sl[t]);
    }
  };

#pragma unroll 1
  for (int phase = 0; phase < 2; ++phase) {
    const int qt = phase ? pairIdx : 15 - pairIdx;  // long tile first
    const int q0 = qt * 128;
    const int nkb = qt + 1;                         // 128-wide KV tiles
    const int wrow0 = q0 + g * 32;
    const int qrow = wrow0 + lq;

    STAGE(0, 0);
    short8 qf[8];
#pragma unroll
    for (int ds = 0; ds < 8; ++ds)
      qf[ds] = *(const short8*)(qkv + (rowbase + qrow) * 3072 + h * 128 + ds * 16 + hi * 8);

    f32x16 acc[4];
#pragma unroll
    for (int dt = 0; dt < 4; ++dt)
#pragma unroll
      for (int jj = 0; jj < 16; ++jj) acc[dt][jj] = 0.f;
    float mrun = -1e30f, lrun = 0.f;

    __syncthreads();   // tile 0 resident

#pragma unroll 1
    for (int kb = 0; kb < nkb; ++kb) {
      const int cur = kb & 1;
      if (kb + 1 < nkb) STAGE(kb + 1, cur ^ 1);   // prefetch overlaps compute
      const int j0 = kb * 128;
      if (j0 + hh * 64 <= wrow0) {                // wave-active (exact; see notes)
        const int kbb = cur * 32768;
        const int vbb = 65536 + cur * 32768;
        // ---- S^T = K @ Q^T : 2 subtiles of 32x32; k = (jj&3)+8*(jj>>2)+4hi + 32t
        f32x16 s0, s1;
#pragma unroll
        for (int jj = 0; jj < 16; ++jj) { s0[jj] = 0.f; s1[jj] = 0.f; }
        __builtin_amdgcn_s_setprio(1);
#pragma unroll
        for (int ds = 0; ds < 8; ++ds) {
          short8 kf = *(const short8*)(smc + kbb + krow + oxk[ds]);
          s0 = __builtin_amdgcn_mfma_f32_32x32x16_bf16(kf, qf[ds], s0, 0, 0, 0);
        }
#pragma unroll
        for (int ds = 0; ds < 8; ++ds) {
          short8 kf = *(const short8*)(smc + kbb + 8192 + krow + oxk[ds]);
          s1 = __builtin_amdgcn_mfma_f32_32x32x16_bf16(kf, qf[ds], s1, 0, 0, 0);
        }
        __builtin_amdgcn_s_setprio(0);
        // ---- causal mask (local to this wave's k-half) ----
        const int rq = qrow - j0 - hh * 64;
        if (rq < 63) {
#pragma unroll
          for (int jj = 0; jj < 16; ++jj) {
            int kl = (jj & 3) + 8 * (jj >> 2) + 4 * hi;
            s0[jj] = (kl > rq) ? -1e30f : s0[jj];
            s1[jj] = (kl + 32 > rq) ? -1e30f : s1[jj];
          }
        }
        // ---- online softmax (exp2 units), T13 defer-max ----
        float pmax = s0[0];
#pragma unroll
        for (int jj = 0; jj < 16; ++jj) pmax = fmaxf(pmax, fmaxf(s0[jj], s1[jj]));
        pmax = fmaxf(pmax, __shfl_xor(pmax, 32));
        if (!__all(pmax - mrun <= 11.5f)) {
          float mn = fmaxf(mrun, pmax);
          float corr = exp2f(mrun - mn);
          lrun *= corr;
#pragma unroll
          for (int dt = 0; dt < 4; ++dt)
#pragma unroll
            for (int jj = 0; jj < 16; ++jj) acc[dt][jj] *= corr;
          mrun = mn;
        }
        float rs = 0.f;
#pragma unroll
        for (int jj = 0; jj < 16; ++jj) {
          s0[jj] = exp2f(s0[jj] - mrun); rs += s0[jj];
          s1[jj] = exp2f(s1[jj] - mrun); rs += s1[jj];
        }
        rs += __shfl_xor(rs, 32);
        lrun += rs;
        // ---- P -> bf16 in registers (T12) ----
        unsigned r0[8], r1[8];
#pragma unroll
        for (int j = 0; j < 4; ++j) {
          asm("v_cvt_pk_bf16_f32 %0, %1, %2" : "=v"(r0[2 * j]) : "v"(s0[4 * j]), "v"(s0[4 * j + 1]));
          asm("v_cvt_pk_bf16_f32 %0, %1, %2" : "=v"(r0[2 * j + 1]) : "v"(s0[4 * j + 2]), "v"(s0[4 * j + 3]));
          asm("v_cvt_pk_bf16_f32 %0, %1, %2" : "=v"(r1[2 * j]) : "v"(s1[4 * j]), "v"(s1[4 * j + 1]));
          asm("v_cvt_pk_bf16_f32 %0, %1, %2" : "=v"(r1[2 * j + 1]) : "v"(s1[4 * j + 2]), "v"(s1[4 * j + 3]));
        }
        // ---- O^T += V^T @ P^T : B-frags via permlane32_swap; 4 k-slices ----
        __builtin_amdgcn_s_setprio(1);
#pragma unroll
        for (int ksl = 0; ksl < 4; ++ksl) {
          unsigned* rr = (ksl < 2) ? r0 : r1;
          int kk = ksl & 1;
          unsigned w0 = rr[4 * kk], w2 = rr[4 * kk + 2];
          asm("v_permlane32_swap_b32 %0, %1" : "+v"(w0), "+v"(w2));
          unsigned w1 = rr[4 * kk + 1], w3 = rr[4 * kk + 3];
          asm("v_permlane32_swap_b32 %0, %1" : "+v"(w1), "+v"(w3));
          union { unsigned u[4]; short8 s8; } pu;
          pu.u[0] = w0; pu.u[1] = w1; pu.u[2] = w2; pu.u[3] = w3;
          short8 pf = pu.s8;
#pragma unroll
          for (int dt = 0; dt < 4; ++dt) {
            short8 vf = *(const short8*)(smc + vbb + dt * 8192 + vrow + oxv[ksl]);
            acc[dt] = __builtin_amdgcn_mfma_f32_32x32x16_bf16(vf, pf, acc[dt], 0, 0, 0);
          }
        }
        __builtin_amdgcn_s_setprio(0);
      }
      __syncthreads();   // prefetch drained; all waves done with cur bufs
    }
    // ---- split-k merge: upper half-waves spill, lower combine ----
    if (hh) {
#pragma unroll
      for (int dt = 0; dt < 4; ++dt)
#pragma unroll
        for (int q4 = 0; q4 < 4; ++q4) {
          f32x4 v = {acc[dt][4 * q4], acc[dt][4 * q4 + 1], acc[dt][4 * q4 + 2], acc[dt][4 * q4 + 3]};
          *(f32x4*)(smc + mab + ((dt * 64 + q4 * 16) ^ lsw)) = v;
        }
      *(float2*)(smc + mlb) = {mrun, lrun};
    }
    __syncthreads();
    if (!hh) {
      float2 ml = *(const float2*)(smc + mlb);
      float mx = fmaxf(mrun, ml.x);
      float sc0 = exp2f(mrun - mx), sc1 = exp2f(ml.x - mx);
      lrun = lrun * sc0 + ml.y * sc1;
#pragma unroll
      for (int dt = 0; dt < 4; ++dt)
#pragma unroll
        for (int q4 = 0; q4 < 4; ++q4) {
          f32x4 v = *(const f32x4*)(smc + mab + ((dt * 64 + q4 * 16) ^ lsw));
#pragma unroll
          for (int r = 0; r < 4; ++r)
            acc[dt][4 * q4 + r] = acc[dt][4 * q4 + r] * sc0 + v[r] * sc1;
        }
    }
    __syncthreads();   // merge reads done; buffers free for next phase
    if (!hh) {
      // ---- epilogue: O^T[d = dt*32 + r + 8m + 4hi][q=lq] ----
      float linv = 1.0f / lrun;
      unsigned short* yrow = y + (rowbase + qrow) * 2048 + h * 128;
#pragma unroll
      for (int dt = 0; dt < 4; ++dt)
#pragma unroll
        for (int m = 0; m < 4; ++m) {
          uint2 o;
          o.x = pk2(acc[dt][4 * m] * linv, acc[dt][4 * m + 1] * linv);
          o.y = pk2(acc[dt][4 * m + 2] * linv, acc[dt][4 * m + 3] * linv);
          *(uint2*)(yrow + dt * 32 + m * 8 + hi * 4) = o;
        }
    }
  }
}

// ---------------- launch ----------------
extern "C" void kernel_launch(void* const* d_in, const int* in_sizes, int n_in,
                              void* d_out, int out_size, void* d_ws, size_t ws_size,
                              hipStream_t stream) {
  (void)in_sizes; (void)n_in; (void)out_size; (void)ws_size;
  const float* x  = (const float*)d_in[0];
  const float* qw = (const float*)d_in[1];
  const float* kw = (const float*)d_in[2];
  const float* vw = (const float*)d_in[3];
  const float* ow = (const float*)d_in[4];
  const float* qg = (const float*)d_in[5];

  char* ws = (char*)d_ws;
  unsigned short* xb   = (unsigned short*)(ws + 0);          // dead after gemm1
  unsigned short* vtg  = (unsigned short*)(ws + 0);          // aliases xb (4 MB)
  unsigned short* wqkv = (unsigned short*)(ws + 16777216);
  unsigned short* owb  = (unsigned short*)(ws + 29360128);
  unsigned short* qkvb = (unsigned short*)(ws + 37748736);
  unsigned short* y    = (unsigned short*)(ws + 62914560);
  float* cost          = (float*)(ws + 79691776);
  float* sint          = (float*)(ws + 80216064);

  prep_kernel<<<18944, 256, 0, stream>>>(x, qw, kw, vw, ow, xb, wqkv, owb, cost, sint);
  gemm8ph<4, 384, 0><<<256, 512, 131072, stream>>>(xb, wqkv, qkvb, 32, 8, 3072, 2048);
  normrope_vt_kernel<<<20736, 256, 0, stream>>>(qkvb, cost, sint, qg, vtg);
  attn_fa10<<<256, 512, 131072, stream>>>(qkvb, vtg, y);
  gemm8ph<4, 256, 1><<<256, 512, 98304, stream>>>(y, owb, d_out, 32, 8, 2048, 2048);
}